// Round 9
// baseline (143.562 us; speedup 1.0000x reference)
//
#include <hip/hip_runtime.h>
#include <hip/hip_bf16.h>

#define HW   8192
#define W0   128
#define H0   64
#define CDIM 256

typedef _Float16 half2v __attribute__((ext_vector_type(2)));

__device__ __forceinline__ float dot2u(unsigned int a, unsigned int b, float acc) {
    union { unsigned int u; half2v h; } ua, ub;
    ua.u = a; ub.u = b;
#if __has_builtin(__builtin_amdgcn_fdot2)
    return __builtin_amdgcn_fdot2(ua.h, ub.h, acc, false);
#else
    return acc + (float)ua.h.x * (float)ub.h.x + (float)ua.h.y * (float)ub.h.y;
#endif
}

// ---------- K1: transpose fmap1 [256][8192] -> f1T [8192][256] f16, scaled 1/16 ----------
__global__ __launch_bounds__(256) void k_transpose_f1(const float* __restrict__ in,
                                                      _Float16* __restrict__ outT) {
    __shared__ float lds[32][257];
    const int m0 = blockIdx.x * 32;
    const int tc = threadIdx.x & 31;
    const int tr = threadIdx.x >> 5;
    #pragma unroll 4
    for (int r = 0; r < 32; ++r) {
        const int c = r * 8 + tr;
        lds[tc][c] = in[(size_t)c * HW + m0 + tc] * 0.0625f;
    }
    __syncthreads();
    const int c = threadIdx.x;
    #pragma unroll 4
    for (int ml = 0; ml < 32; ++ml) {
        outT[(size_t)(m0 + ml) * CDIM + c] = (_Float16)lds[ml][c];
    }
}

// ---------- K2: transpose fmap2 [256][8192] -> pyramid level0 HWC f16 ----------
__global__ __launch_bounds__(256) void k_transpose_f2(const float* __restrict__ in,
                                                      _Float16* __restrict__ outT) {
    __shared__ float lds[32][257];
    const int m0 = blockIdx.x * 32;
    const int tc = threadIdx.x & 31;
    const int tr = threadIdx.x >> 5;
    #pragma unroll 4
    for (int r = 0; r < 32; ++r) {
        const int c = r * 8 + tr;
        lds[tc][c] = in[(size_t)c * HW + m0 + tc];
    }
    __syncthreads();
    const int c = threadIdx.x;
    #pragma unroll 4
    for (int ml = 0; ml < 32; ++ml) {
        outT[(size_t)(m0 + ml) * CDIM + c] = (_Float16)lds[ml][c];
    }
}

// ---------- K3: 2x2 avg pool, HWC f16 -> HWC f16 ----------
__global__ __launch_bounds__(256) void k_pool(const _Float16* __restrict__ in,
                                              _Float16* __restrict__ out,
                                              int Wout, int Win) {
    const int c = threadIdx.x;
    const int b = blockIdx.x;           // Y*Wout + X
    const int X = b % Wout;
    const int Y = b / Wout;
    const size_t base = ((size_t)(2 * Y) * Win + 2 * X) * CDIM + c;
    const size_t rows = (size_t)Win * CDIM;
    float s = (float)in[base] + (float)in[base + CDIM] +
              (float)in[base + rows] + (float)in[base + rows + CDIM];
    out[(size_t)b * CDIM + c] = (_Float16)(s * 0.25f);
}

// ---------- K4: fused correlation sampling ----------
// 512 blocks x 1024 threads (16 waves). Wave wv = pixel m0+wv, all 4 levels.
// 32 lanes per grid point (8 ch / lane), 2 points per wave-instruction:
// a window row (10 texels = 5 KB) is contiguous; each load instr covers ~2
// contiguous 512-B segments (vs 8 scattered 128-B before). Branch-free:
// clamped addresses + mask multiply; 5 loads per row issued back-to-back.
__global__ __launch_bounds__(1024, 4) void k_sample(const _Float16* __restrict__ f1T,
                                                    const _Float16* __restrict__ pyr,
                                                    const float* __restrict__ coords,
                                                    float* __restrict__ out) {
    const int tid  = threadIdx.x;
    const int wv   = tid >> 6;      // wave = pixel within block (0..15)
    const int lane = tid & 63;
    const int pg   = lane >> 5;     // which point of the pair
    const int sub  = lane & 31;     // channel-lane: ch [sub*8, sub*8+8)
    const int m0   = blockIdx.x * 16;
    const int m    = m0 + wv;

    __shared__ float sG[16][4][105];  // px-stride 420 floats -> bank offset 4/px
    __shared__ float sF[16][4][2];    // fx, fy

    // f1 fragment: 8 channels (16 B) per lane, reused across 4 levels x 100 pts
    const uint4 F = *reinterpret_cast<const uint4*>(f1T + (size_t)m * CDIM + sub * 8);

    const float cx = coords[m];
    const float cy = coords[HW + m];

    #pragma unroll
    for (int w = 0; w < 4; ++w) {
        const int Wl = W0 >> w;
        const int Hl = H0 >> w;
        const size_t lvl_off = (w == 0) ? 0u
                             : (w == 1) ? 2097152u
                             : (w == 2) ? 2621440u
                             :            2752512u;
        const _Float16* lvl = pyr + lvl_off;
        const float scale = 1.0f / (float)(1 << w);

        const float xs = cx * scale;
        const float ys = cy * scale;
        const float X0f = floorf(xs), Y0f = floorf(ys);
        const int X0 = (int)X0f, Y0 = (int)Y0f;
        if (lane == 0) { sF[wv][w][0] = xs - X0f; sF[wv][w][1] = ys - Y0f; }

        for (int j = 0; j < 10; ++j) {
            const int gy   = Y0 - 4 + j;
            const int cyc  = min(max(gy, 0), Hl - 1);
            const float ym = ((unsigned)gy < (unsigned)Hl) ? 1.0f : 0.0f;
            const _Float16* row = lvl + (size_t)cyc * Wl * CDIM;
            #pragma unroll
            for (int t = 0; t < 5; ++t) {
                const int i   = t * 2 + pg;
                const int gx  = X0 - 4 + i;
                const int cxc = min(max(gx, 0), Wl - 1);
                const float msk = ((unsigned)gx < (unsigned)Wl) ? ym : 0.0f;
                const uint4 q = *reinterpret_cast<const uint4*>(
                    row + (size_t)cxc * CDIM + sub * 8);
                float s = 0.0f;
                s = dot2u(q.x, F.x, s);
                s = dot2u(q.y, F.y, s);
                s = dot2u(q.z, F.z, s);
                s = dot2u(q.w, F.w, s);
                s *= msk;
                // reduce across the 32 lanes of this point (xor<=16 stays in half)
                s += __shfl_xor(s, 1);
                s += __shfl_xor(s, 2);
                s += __shfl_xor(s, 4);
                s += __shfl_xor(s, 8);
                s += __shfl_xor(s, 16);
                if (sub == 0) sG[wv][w][j * 10 + i] = s;
            }
        }
    }
    __syncthreads();

    // combine: thread t -> pixel (t&15), outputs (t>>4) + k*64
    const int cpx = tid & 15;
    for (int o = tid >> 4; o < 324; o += 64) {
        const int lev = (o * 811) >> 16;          // o / 81
        const int k   = o - lev * 81;
        const int a   = (k * 57) >> 9;            // k / 9  (x-offset index)
        const int bb  = k - a * 9;                // k % 9  (y-offset index)
        const float fx = sF[cpx][lev][0], fy = sF[cpx][lev][1];
        const float wx0 = 1.0f - fx, wy0 = 1.0f - fy;
        const float* G = sG[cpx][lev];
        const float v = wy0 * (wx0 * G[bb * 10 + a]       + fx * G[bb * 10 + a + 1])
                      + fy  * (wx0 * G[(bb + 1) * 10 + a] + fx * G[(bb + 1) * 10 + a + 1]);
        out[(size_t)o * HW + m0 + cpx] = v;
    }
}

extern "C" void kernel_launch(void* const* d_in, const int* in_sizes, int n_in,
                              void* d_out, int out_size, void* d_ws, size_t ws_size,
                              hipStream_t stream) {
    const float* fmap1  = (const float*)d_in[0];
    const float* fmap2  = (const float*)d_in[1];
    const float* coords = (const float*)d_in[2];
    float* out = (float*)d_out;

    char* ws = (char*)d_ws;
    _Float16* f1T = (_Float16*)ws;                          // 8192*256 f16 = 4 MiB
    _Float16* pyr = (_Float16*)(ws + 4194304);              // 2,785,280 f16 = 5.57 MB
    _Float16* p0 = pyr;                 // 64x128x256
    _Float16* p1 = pyr + 2097152;       // 32x64x256
    _Float16* p2 = pyr + 2621440;       // 16x32x256
    _Float16* p3 = pyr + 2752512;       //  8x16x256

    k_transpose_f1<<<HW / 32, 256, 0, stream>>>(fmap1, f1T);
    k_transpose_f2<<<HW / 32, 256, 0, stream>>>(fmap2, p0);
    k_pool<<<32 * 64, 256, 0, stream>>>(p0, p1, 64, 128);
    k_pool<<<16 * 32, 256, 0, stream>>>(p1, p2, 32, 64);
    k_pool<<<8 * 16, 256, 0, stream>>>(p2, p3, 16, 32);
    k_sample<<<HW / 16, 1024, 0, stream>>>(f1T, pyr, coords, out);
}

// Round 10
// 79.542 us; speedup vs baseline: 1.8049x; 1.8049x over previous
//
#include <hip/hip_runtime.h>
#include <hip/hip_bf16.h>

#define HW   8192
#define W0   128
#define H0   64
#define CDIM 256

__device__ __forceinline__ int dot4(unsigned int a, unsigned int b, int acc) {
#if __has_builtin(__builtin_amdgcn_sdot4)
    return __builtin_amdgcn_sdot4((int)a, (int)b, acc, false);
#else
    int r = acc;
    #pragma unroll
    for (int k = 0; k < 4; ++k) {
        r += (int)(signed char)(a >> (8 * k)) * (int)(signed char)(b >> (8 * k));
    }
    return r;
#endif
}

// ---------- K1: transpose+quantize fmap1 -> q1[8192][256] int8, s1[8192] ----------
// s1 folds the 1/16 correlation scale.
__global__ __launch_bounds__(256) void k_q_f1(const float* __restrict__ in,
                                              signed char* __restrict__ q1,
                                              float* __restrict__ s1) {
    __shared__ float lds[32][257];
    __shared__ float sInv[32];
    __shared__ float sSc[32];
    const int m0 = blockIdx.x * 32;
    const int tc = threadIdx.x & 31;
    const int tr = threadIdx.x >> 5;
    #pragma unroll 4
    for (int r = 0; r < 32; ++r) {
        const int c = r * 8 + tr;
        lds[tc][c] = in[(size_t)c * HW + m0 + tc];
    }
    __syncthreads();
    // per-row absmax: 8 threads per row
    const int row = threadIdx.x >> 3, t8 = threadIdx.x & 7;
    float am = 0.f;
    #pragma unroll 8
    for (int k = 0; k < 32; ++k) am = fmaxf(am, fabsf(lds[row][t8 * 32 + k]));
    am = fmaxf(am, __shfl_xor(am, 1));
    am = fmaxf(am, __shfl_xor(am, 2));
    am = fmaxf(am, __shfl_xor(am, 4));
    if (t8 == 0) {
        sInv[row] = am > 0.f ? 127.f / am : 0.f;
        sSc[row]  = (am / 127.f) * 0.0625f;
    }
    __syncthreads();
    const int c = threadIdx.x;
    #pragma unroll 4
    for (int ml = 0; ml < 32; ++ml) {
        q1[(size_t)(m0 + ml) * CDIM + c] =
            (signed char)__float2int_rn(lds[ml][c] * sInv[ml]);
    }
    if (threadIdx.x < 32) s1[m0 + threadIdx.x] = sSc[threadIdx.x];
}

// ---------- K2: transpose fmap2 [256][8192] -> pyramid level0 HWC f16 ----------
__global__ __launch_bounds__(256) void k_transpose_f2(const float* __restrict__ in,
                                                      _Float16* __restrict__ outT) {
    __shared__ float lds[32][257];
    const int m0 = blockIdx.x * 32;
    const int tc = threadIdx.x & 31;
    const int tr = threadIdx.x >> 5;
    #pragma unroll 4
    for (int r = 0; r < 32; ++r) {
        const int c = r * 8 + tr;
        lds[tc][c] = in[(size_t)c * HW + m0 + tc];
    }
    __syncthreads();
    const int c = threadIdx.x;
    #pragma unroll 4
    for (int ml = 0; ml < 32; ++ml) {
        outT[(size_t)(m0 + ml) * CDIM + c] = (_Float16)lds[ml][c];
    }
}

// ---------- K3: 2x2 avg pool, HWC f16 -> HWC f16 ----------
__global__ __launch_bounds__(256) void k_pool(const _Float16* __restrict__ in,
                                              _Float16* __restrict__ out,
                                              int Wout, int Win) {
    const int c = threadIdx.x;
    const int b = blockIdx.x;
    const int X = b % Wout;
    const int Y = b / Wout;
    const size_t base = ((size_t)(2 * Y) * Win + 2 * X) * CDIM + c;
    const size_t rows = (size_t)Win * CDIM;
    float s = (float)in[base] + (float)in[base + CDIM] +
              (float)in[base + rows] + (float)in[base + rows + CDIM];
    out[(size_t)b * CDIM + c] = (_Float16)(s * 0.25f);
}

// ---------- K3b: per-texel int8 quantization of the pyramid ----------
// one texel (256 ch) per wave; 4 waves/block.
__global__ __launch_bounds__(256) void k_quant(const _Float16* __restrict__ pf,
                                               unsigned int* __restrict__ pq,
                                               float* __restrict__ s2, int ntex) {
    const int t = blockIdx.x * 4 + (threadIdx.x >> 6);
    if (t >= ntex) return;
    const int lane = threadIdx.x & 63;
    const _Float16* p = pf + (size_t)t * CDIM + lane * 4;
    const float a0 = (float)p[0], a1 = (float)p[1], a2 = (float)p[2], a3 = (float)p[3];
    float am = fmaxf(fmaxf(fabsf(a0), fabsf(a1)), fmaxf(fabsf(a2), fabsf(a3)));
    #pragma unroll
    for (int d = 1; d < 64; d <<= 1) am = fmaxf(am, __shfl_xor(am, d));
    const float inv = am > 0.f ? 127.f / am : 0.f;
    const unsigned int q0 = (unsigned int)__float2int_rn(a0 * inv) & 255u;
    const unsigned int q1 = (unsigned int)__float2int_rn(a1 * inv) & 255u;
    const unsigned int q2 = (unsigned int)__float2int_rn(a2 * inv) & 255u;
    const unsigned int q3 = (unsigned int)__float2int_rn(a3 * inv) & 255u;
    pq[(size_t)t * 64 + lane] = q0 | (q1 << 8) | (q2 << 16) | (q3 << 24);
    if (lane == 0) s2[t] = am / 127.f;
}

// ---------- K4: fused correlation sampling, int8 dot4 ----------
// 512 blocks x 1024 threads (16 waves). Wave wv = pixel m0+wv, all 4 levels.
// 8 lanes per point, 32 ch (32 B int8) per lane: 2 uint4 loads, 8 v_dot4,
// 3-step integer shuffle reduce. Per-point scale s2[texel]; per-pixel s1
// applied in the combine phase.
__global__ __launch_bounds__(1024, 4) void k_sample(const signed char* __restrict__ q1,
                                                    const float* __restrict__ s1,
                                                    const unsigned char* __restrict__ pyrQ,
                                                    const float* __restrict__ s2,
                                                    const float* __restrict__ coords,
                                                    float* __restrict__ out) {
    const int tid  = threadIdx.x;
    const int wv   = tid >> 6;
    const int lane = tid & 63;
    const int grp  = lane >> 3;
    const int sub  = lane & 7;
    const int m0   = blockIdx.x * 16;
    const int m    = m0 + wv;

    __shared__ float sG[16][4][105];
    __shared__ float sF[16][4][2];
    __shared__ float sS[16];

    if (tid < 16) sS[tid] = s1[m0 + tid];

    // f1 fragment: 32 channels (32 B int8) per lane
    const uint4* f1p = reinterpret_cast<const uint4*>(q1 + (size_t)m * CDIM + sub * 32);
    const uint4 Fa = f1p[0], Fb = f1p[1];

    const float cx = coords[m];
    const float cy = coords[HW + m];

    #pragma unroll
    for (int w = 0; w < 4; ++w) {
        const int Wl = W0 >> w;
        const int Hl = H0 >> w;
        const int texoff = (w == 0) ? 0 : (w == 1) ? 8192 : (w == 2) ? 10240 : 10752;
        const unsigned char* lvl = pyrQ + ((size_t)texoff << 8);
        const float* s2l = s2 + texoff;
        const float scale = 1.0f / (float)(1 << w);

        const float xs = cx * scale;
        const float ys = cy * scale;
        const float X0f = floorf(xs), Y0f = floorf(ys);
        const int X0 = (int)X0f, Y0 = (int)Y0f;
        if (lane == 0) { sF[wv][w][0] = xs - X0f; sF[wv][w][1] = ys - Y0f; }

        for (int it = 0; it < 13; ++it) {
            const int p = it * 8 + grp;           // grid point 0..103 (mask >=100)
            const int j = (p * 205) >> 11;        // p / 10
            const int i = p - j * 10;
            const int gy = Y0 - 4 + j;
            const int gx = X0 - 4 + i;
            const bool ok = (p < 100) && ((unsigned)gy < (unsigned)Hl) &&
                            ((unsigned)gx < (unsigned)Wl);
            int acc = 0;
            if (ok) {
                const uint4* q = reinterpret_cast<const uint4*>(
                    lvl + (((size_t)(gy * Wl + gx)) << 8) + sub * 32);
                const uint4 A = q[0], B = q[1];
                acc = dot4(A.x, Fa.x, acc); acc = dot4(A.y, Fa.y, acc);
                acc = dot4(A.z, Fa.z, acc); acc = dot4(A.w, Fa.w, acc);
                acc = dot4(B.x, Fb.x, acc); acc = dot4(B.y, Fb.y, acc);
                acc = dot4(B.z, Fb.z, acc); acc = dot4(B.w, Fb.w, acc);
            }
            acc += __shfl_xor(acc, 1);
            acc += __shfl_xor(acc, 2);
            acc += __shfl_xor(acc, 4);
            float gv = 0.f;
            if (ok) gv = (float)acc * s2l[gy * Wl + gx];
            if (sub == 0 && p < 100) sG[wv][w][p] = gv;
        }
    }
    __syncthreads();

    const int cpx = tid & 15;
    const float s1v = sS[cpx];
    for (int o = tid >> 4; o < 324; o += 64) {
        const int lev = (o * 811) >> 16;          // o / 81
        const int k   = o - lev * 81;
        const int a   = (k * 57) >> 9;            // k / 9  (x-offset index)
        const int bb  = k - a * 9;                // k % 9  (y-offset index)
        const float fx = sF[cpx][lev][0], fy = sF[cpx][lev][1];
        const float wx0 = 1.0f - fx, wy0 = 1.0f - fy;
        const float* G = sG[cpx][lev];
        const float v = wy0 * (wx0 * G[bb * 10 + a]       + fx * G[bb * 10 + a + 1])
                      + fy  * (wx0 * G[(bb + 1) * 10 + a] + fx * G[(bb + 1) * 10 + a + 1]);
        out[(size_t)o * HW + m0 + cpx] = v * s1v;
    }
}

extern "C" void kernel_launch(void* const* d_in, const int* in_sizes, int n_in,
                              void* d_out, int out_size, void* d_ws, size_t ws_size,
                              hipStream_t stream) {
    const float* fmap1  = (const float*)d_in[0];
    const float* fmap2  = (const float*)d_in[1];
    const float* coords = (const float*)d_in[2];
    float* out = (float*)d_out;

    char* ws = (char*)d_ws;
    // layout (bytes):
    signed char* q1  = (signed char*)ws;                    // 2,097,152
    float* s1        = (float*)(ws + 2097152);              // 32,768
    float* s2        = (float*)(ws + 2129920);              // 43,520
    unsigned char* pyrQ = (unsigned char*)(ws + 2176000);   // 2,785,280
    _Float16* pyrF   = (_Float16*)(ws + 4961280);           // 5,570,560
    _Float16* p0 = pyrF;                // 64x128x256
    _Float16* p1 = pyrF + 2097152;      // 32x64x256
    _Float16* p2 = pyrF + 2621440;      // 16x32x256
    _Float16* p3 = pyrF + 2752512;      //  8x16x256

    k_transpose_f2<<<HW / 32, 256, 0, stream>>>(fmap2, p0);
    k_pool<<<32 * 64, 256, 0, stream>>>(p0, p1, 64, 128);
    k_pool<<<16 * 32, 256, 0, stream>>>(p1, p2, 32, 64);
    k_pool<<<8 * 16, 256, 0, stream>>>(p2, p3, 16, 32);
    k_quant<<<(10880 + 3) / 4, 256, 0, stream>>>(pyrF, (unsigned int*)pyrQ, s2, 10880);
    k_q_f1<<<HW / 32, 256, 0, stream>>>(fmap1, q1, s1);
    k_sample<<<HW / 16, 1024, 0, stream>>>(q1, s1, pyrQ, s2, coords, out);
}